// Round 2
// baseline (291.420 us; speedup 1.0000x reference)
//
#include <hip/hip_runtime.h>

// Shapes (fixed by the problem)
#define NB 4
#define LL 2048
#define SS 2048
#define HH 16
#define EE 64
#define DD 64

#define KVTOT (2*NB*HH*4096)   // 524288 floats of KV tiles
#define WSFLOATS (KVTOT + 2*NB*HH*64)

__device__ inline float phi(float x) { return x > 0.f ? x + 1.f : __expf(x); }

// ---------------- Phase 1: KV[d][m] = sum_s phi(K)[s,d]*V[s,m]; Ksum[d] ----------------
// grid: 1024 = st(2) * n(4) * h(16) * schunk(8); block: 256
__global__ __launch_bounds__(256) void kv_kernel(
    const float* __restrict__ k1, const float* __restrict__ v1,
    const float* __restrict__ k2, const float* __restrict__ v2,
    const float* __restrict__ kl1, const float* __restrict__ kl2,
    float* __restrict__ ws)
{
    const int b = blockIdx.x;
    const int chunk = b & 7;
    const int h = (b >> 3) & 15;
    const int n = (b >> 7) & 3;
    const int st = (b >> 9) & 1;
    const float* K  = st == 0 ? k2 : k1;   // stream0: Q1 attends K2/V2
    const float* V  = st == 0 ? v2 : v1;
    const float* KL = st == 0 ? kl2 : kl1;

    const int t = threadIdx.x;
    __shared__ float Kl[16][68];  // pad 68: 16B-aligned float4 rows, <=2-way banks
    __shared__ float Vl[16][68];

    const int r  = t >> 4;          // staging row 0..15
    const int c4 = (t & 15) * 4;    // staging col 0..60
    const int d0 = (t >> 4) * 4;    // tile: 4 d-values
    const int m0 = (t & 15) * 4;    // tile: 4 m-values

    float acc[4][4];
#pragma unroll
    for (int i = 0; i < 4; i++)
#pragma unroll
        for (int j = 0; j < 4; j++) acc[i][j] = 0.f;
    float ks = 0.f;

    const int sbase = chunk * 256;
    for (int stage = 0; stage < 16; stage++) {
        __syncthreads();
        // ---- stage 16 rows of K (phi * keylen) and V into LDS ----
        {
            const int s = sbase + stage * 16 + r;
            const size_t rowoff = ((size_t)(((size_t)n * SS + s) * HH + h)) * EE;
            float4 kf = *reinterpret_cast<const float4*>(&K[rowoff + c4]);
            float4 vf = *reinterpret_cast<const float4*>(&V[rowoff + c4]);
            const float kl = KL[(size_t)n * SS + s];
            Kl[r][c4 + 0] = phi(kf.x) * kl;
            Kl[r][c4 + 1] = phi(kf.y) * kl;
            Kl[r][c4 + 2] = phi(kf.z) * kl;
            Kl[r][c4 + 3] = phi(kf.w) * kl;
            Vl[r][c4 + 0] = vf.x;
            Vl[r][c4 + 1] = vf.y;
            Vl[r][c4 + 2] = vf.z;
            Vl[r][c4 + 3] = vf.w;
        }
        __syncthreads();
        // ---- outer-product accumulate over the 16 staged rows ----
#pragma unroll
        for (int s2 = 0; s2 < 16; s2++) {
            float4 kk = *reinterpret_cast<const float4*>(&Kl[s2][d0]);
            float4 vv = *reinterpret_cast<const float4*>(&Vl[s2][m0]);
            float ka[4] = {kk.x, kk.y, kk.z, kk.w};
            float va[4] = {vv.x, vv.y, vv.z, vv.w};
#pragma unroll
            for (int i = 0; i < 4; i++)
#pragma unroll
                for (int j = 0; j < 4; j++) acc[i][j] += ka[i] * va[j];
        }
        if (t < 64) {
#pragma unroll
            for (int s2 = 0; s2 < 16; s2++) ks += Kl[s2][t];
        }
    }

    const size_t kvbase = ((size_t)((st * NB + n) * HH + h)) * 4096;
#pragma unroll
    for (int i = 0; i < 4; i++)
#pragma unroll
        for (int j = 0; j < 4; j++)
            atomicAdd(&ws[kvbase + (size_t)(d0 + i) * 64 + (m0 + j)], acc[i][j]);
    if (t < 64)
        atomicAdd(&ws[KVTOT + ((size_t)(st * NB + n) * HH + h) * 64 + t], ks);
}

// ---------------- Phase 2: out[l,m] = (sum_d phi(Q)[l,d]*KV[d,m]) * Z[l] ----------------
// grid: 2048 = st(2) * n(4) * h(16) * lchunk(16, 128 rows each); block: 256
__global__ __launch_bounds__(256) void out_kernel(
    const float* __restrict__ q1, const float* __restrict__ q2,
    const float* __restrict__ ws, float* __restrict__ out)
{
    const int b = blockIdx.x;
    const int lc = b & 15;
    const int h = (b >> 4) & 15;
    const int n = (b >> 8) & 3;
    const int st = (b >> 10) & 1;
    const float* Q = st == 0 ? q1 : q2;
    const size_t outoff = (size_t)st * ((size_t)NB * LL * HH * DD);

    __shared__ float T[4096];      // T[d*64+m] = KV[d][m]
    __shared__ float Qt[64][132];  // Qt[d][l], padded 128->132
    __shared__ float Zl[128];
    __shared__ float Ks[64];

    const int t = threadIdx.x;
    const size_t kvbase = ((size_t)((st * NB + n) * HH + h)) * 4096;
#pragma unroll
    for (int i = 0; i < 16; i++) T[i * 256 + t] = ws[kvbase + i * 256 + t];
    if (t < 64) Ks[t] = ws[KVTOT + ((size_t)(st * NB + n) * HH + h) * 64 + t];

    // ---- stage phi(Q) transposed: each thread loads 32 floats of one l-row ----
    {
        const int l = t >> 1;
        const int dd0 = (t & 1) * 32;
        const int lg = lc * 128 + l;
        const size_t qoff = ((size_t)(((size_t)n * LL + lg) * HH + h)) * EE + dd0;
#pragma unroll
        for (int i = 0; i < 8; i++) {
            float4 qu = *reinterpret_cast<const float4*>(&Q[qoff + i * 4]);
            const int db = dd0 + i * 4;
            Qt[db + 0][l] = phi(qu.x);
            Qt[db + 1][l] = phi(qu.y);
            Qt[db + 2][l] = phi(qu.z);
            Qt[db + 3][l] = phi(qu.w);
        }
    }
    __syncthreads();

    // ---- Z[l] = 1/(phi(Q)[l]·Ksum + eps) ----
    if (t < 128) {
        float z = 0.f;
#pragma unroll
        for (int d = 0; d < 64; d++) z += Qt[d][t] * Ks[d];
        Zl[t] = 1.f / (z + 1e-6f);
    }
    __syncthreads();

    // ---- register-tiled GEMM: thread = 8 l x 4 m ----
    const int m0 = (t & 15) * 4;
    const int l0 = (t >> 4) * 8;
    float acc[8][4];
#pragma unroll
    for (int i = 0; i < 8; i++)
#pragma unroll
        for (int j = 0; j < 4; j++) acc[i][j] = 0.f;

    for (int d = 0; d < 64; d++) {
        float4 tv = *reinterpret_cast<const float4*>(&T[d * 64 + m0]);
        float4 qa = *reinterpret_cast<const float4*>(&Qt[d][l0]);
        float4 qb = *reinterpret_cast<const float4*>(&Qt[d][l0 + 4]);
        float tm[4] = {tv.x, tv.y, tv.z, tv.w};
        float ql[8] = {qa.x, qa.y, qa.z, qa.w, qb.x, qb.y, qb.z, qb.w};
#pragma unroll
        for (int i = 0; i < 8; i++)
#pragma unroll
            for (int j = 0; j < 4; j++) acc[i][j] += ql[i] * tm[j];
    }

    // ---- epilogue: scale by Z, store float4 per row ----
#pragma unroll
    for (int i = 0; i < 8; i++) {
        const int l = l0 + i;
        const int lg = lc * 128 + l;
        const float z = Zl[l];
        float4 o;
        o.x = acc[i][0] * z;
        o.y = acc[i][1] * z;
        o.z = acc[i][2] * z;
        o.w = acc[i][3] * z;
        *reinterpret_cast<float4*>(
            &out[outoff + ((size_t)(((size_t)n * LL + lg) * HH + h)) * DD + m0]) = o;
    }
}

extern "C" void kernel_launch(void* const* d_in, const int* in_sizes, int n_in,
                              void* d_out, int out_size, void* d_ws, size_t ws_size,
                              hipStream_t stream) {
    const float* q1  = (const float*)d_in[0];
    const float* k1  = (const float*)d_in[1];
    const float* v1  = (const float*)d_in[2];
    const float* q2  = (const float*)d_in[3];
    const float* k2  = (const float*)d_in[4];
    const float* v2  = (const float*)d_in[5];
    const float* kl1 = (const float*)d_in[6];
    const float* kl2 = (const float*)d_in[7];
    float* ws = (float*)d_ws;
    float* out = (float*)d_out;

    hipMemsetAsync(d_ws, 0, (size_t)WSFLOATS * sizeof(float), stream);
    kv_kernel<<<dim3(1024), dim3(256), 0, stream>>>(k1, v1, k2, v2, kl1, kl2, ws);
    out_kernel<<<dim3(2048), dim3(256), 0, stream>>>(q1, q2, ws, out);
}

// Round 4
// 253.878 us; speedup vs baseline: 1.1479x; 1.1479x over previous
//
#include <hip/hip_runtime.h>

// Shapes (fixed by the problem)
#define NB 4
#define LL 2048
#define SS 2048
#define HH 16
#define EE 64
#define DD 64

#define KVTOT (2*NB*HH*4096)   // 524288 floats of KVT tiles (stored [m][d])
#define WSFLOATS (KVTOT + 2*NB*HH*64)

typedef short short8 __attribute__((ext_vector_type(8)));
typedef float floatx4 __attribute__((ext_vector_type(4)));

__device__ inline float phi(float x) { return x > 0.f ? x + 1.f : __expf(x); }

// fp32 -> bf16 (RNE), result in low 16 bits
__device__ inline unsigned int f2bf(float f) {
    unsigned int x = __float_as_uint(f);
    return (x + 0x7FFFu + ((x >> 16) & 1u)) >> 16;
}
// split x into hi=bf16(x), lo=bf16(x-hi); pack pairs (a,b) -> (hi-pair, lo-pair)
__device__ inline void split_pack(float a, float b, unsigned int &hp, unsigned int &lp) {
    const unsigned int ha = f2bf(a), hb = f2bf(b);
    const float ra = a - __uint_as_float(ha << 16);
    const float rb = b - __uint_as_float(hb << 16);
    hp = (ha & 0xFFFFu) | (hb << 16);
    lp = (f2bf(ra) & 0xFFFFu) | (f2bf(rb) << 16);
}

// ---------------- Phase 1 (split-bf16 MFMA): KVT[m][d] = sum_s V[s,m]*phiK[s,d]*kl[s] --
// grid: 1024 = st(2)*n(4)*h(16)*schunk(8); block 256 (4 waves); 4 groups of 64 s.
__global__ __launch_bounds__(256) void kv_kernel(
    const float* __restrict__ k1, const float* __restrict__ v1,
    const float* __restrict__ k2, const float* __restrict__ v2,
    const float* __restrict__ kl1, const float* __restrict__ kl2,
    float* __restrict__ ws)
{
    const int b = blockIdx.x;
    const int chunk = b & 7;
    const int h = (b >> 3) & 15;
    const int n = (b >> 7) & 3;
    const int st = (b >> 9) & 1;
    const float* K  = st ? k1 : k2;   // stream0 output attends K2/V2
    const float* V  = st ? v1 : v2;
    const float* KL = st ? kl1 : kl2;

    // Transposed bf16 tiles [row][s]; row stride 72 (=144B, 16B-aligned, conflict-free)
    __shared__ __align__(16) unsigned short KtH[64][72];
    __shared__ __align__(16) unsigned short KtL[64][72];
    __shared__ __align__(16) unsigned short VtH[64][72];
    __shared__ __align__(16) unsigned short VtL[64][72];  // overlaid by scr at the end

    const int t = threadIdx.x;
    const int lane = t & 63;
    const int w = t >> 6;          // wave id: owns m-strip [16w,16w+16)
    const int d4 = t & 15;         // staging: column quad
    const int sp = t >> 4;         // staging: s-pair index 0..15
    const int c = lane & 15;
    const int q = lane >> 4;

    float ksum[4] = {0.f, 0.f, 0.f, 0.f};
    floatx4 acc[4];
#pragma unroll
    for (int i = 0; i < 4; i++) acc[i] = (floatx4){0.f, 0.f, 0.f, 0.f};

    // ---- register prefetch: group g's K/V/kl live in regs one iteration early ----
    float4 cur[8]; float curl[4];
    {
        const int sbase = chunk * 256;
#pragma unroll
        for (int i = 0; i < 2; ++i) {
            const int sl = 2 * sp + 32 * i;
            const size_t off = ((size_t)((size_t)n * SS + sbase + sl) * HH + h) * EE + 4 * d4;
            cur[4 * i + 0] = *(const float4*)&K[off];
            cur[4 * i + 1] = *(const float4*)&K[off + HH * EE];
            cur[4 * i + 2] = *(const float4*)&V[off];
            cur[4 * i + 3] = *(const float4*)&V[off + HH * EE];
            curl[2 * i + 0] = KL[(size_t)n * SS + sbase + sl];
            curl[2 * i + 1] = KL[(size_t)n * SS + sbase + sl + 1];
        }
    }

    for (int g = 0; g < 4; ++g) {
        float4 nxt[8]; float nxtl[4];
        if (g < 3) {
            const int sbase = chunk * 256 + (g + 1) * 64;
#pragma unroll
            for (int i = 0; i < 2; ++i) {
                const int sl = 2 * sp + 32 * i;
                const size_t off = ((size_t)((size_t)n * SS + sbase + sl) * HH + h) * EE + 4 * d4;
                nxt[4 * i + 0] = *(const float4*)&K[off];
                nxt[4 * i + 1] = *(const float4*)&K[off + HH * EE];
                nxt[4 * i + 2] = *(const float4*)&V[off];
                nxt[4 * i + 3] = *(const float4*)&V[off + HH * EE];
                nxtl[2 * i + 0] = KL[(size_t)n * SS + sbase + sl];
                nxtl[2 * i + 1] = KL[(size_t)n * SS + sbase + sl + 1];
            }
        }
        if (g) __syncthreads();   // tiles of group g-1 fully consumed before overwrite
        // ---- stage group g from registers: phi, keylen, hi/lo split ----
#pragma unroll
        for (int i = 0; i < 2; ++i) {
            const int sl = 2 * sp + 32 * i;
            const float4 ka = cur[4 * i + 0], kb = cur[4 * i + 1];
            const float4 va = cur[4 * i + 2], vb = cur[4 * i + 3];
            const float l0 = curl[2 * i + 0], l1 = curl[2 * i + 1];
            const float a0 = phi(ka.x) * l0, a1 = phi(ka.y) * l0;
            const float a2 = phi(ka.z) * l0, a3 = phi(ka.w) * l0;
            const float b0 = phi(kb.x) * l1, b1 = phi(kb.y) * l1;
            const float b2 = phi(kb.z) * l1, b3 = phi(kb.w) * l1;
            ksum[0] += a0 + b0; ksum[1] += a1 + b1;
            ksum[2] += a2 + b2; ksum[3] += a3 + b3;
            unsigned int hp, lp;
            split_pack(a0, b0, hp, lp);
            *(unsigned int*)&KtH[4 * d4 + 0][sl] = hp; *(unsigned int*)&KtL[4 * d4 + 0][sl] = lp;
            split_pack(a1, b1, hp, lp);
            *(unsigned int*)&KtH[4 * d4 + 1][sl] = hp; *(unsigned int*)&KtL[4 * d4 + 1][sl] = lp;
            split_pack(a2, b2, hp, lp);
            *(unsigned int*)&KtH[4 * d4 + 2][sl] = hp; *(unsigned int*)&KtL[4 * d4 + 2][sl] = lp;
            split_pack(a3, b3, hp, lp);
            *(unsigned int*)&KtH[4 * d4 + 3][sl] = hp; *(unsigned int*)&KtL[4 * d4 + 3][sl] = lp;
            split_pack(va.x, vb.x, hp, lp);
            *(unsigned int*)&VtH[4 * d4 + 0][sl] = hp; *(unsigned int*)&VtL[4 * d4 + 0][sl] = lp;
            split_pack(va.y, vb.y, hp, lp);
            *(unsigned int*)&VtH[4 * d4 + 1][sl] = hp; *(unsigned int*)&VtL[4 * d4 + 1][sl] = lp;
            split_pack(va.z, vb.z, hp, lp);
            *(unsigned int*)&VtH[4 * d4 + 2][sl] = hp; *(unsigned int*)&VtL[4 * d4 + 2][sl] = lp;
            split_pack(va.w, vb.w, hp, lp);
            *(unsigned int*)&VtH[4 * d4 + 3][sl] = hp; *(unsigned int*)&VtL[4 * d4 + 3][sl] = lp;
        }
        __syncthreads();
        // ---- 3-term split MFMA: Vh*Kh + Vh*Kl + Vl*Kh ----
#pragma unroll
        for (int ks = 0; ks < 2; ++ks) {
            const short8 aH = *(const short8*)&VtH[16 * w + c][32 * ks + 8 * q];
            const short8 aL = *(const short8*)&VtL[16 * w + c][32 * ks + 8 * q];
#pragma unroll
            for (int dt = 0; dt < 4; ++dt) {
                const short8 bH = *(const short8*)&KtH[16 * dt + c][32 * ks + 8 * q];
                const short8 bL = *(const short8*)&KtL[16 * dt + c][32 * ks + 8 * q];
                acc[dt] = __builtin_amdgcn_mfma_f32_16x16x32_bf16(aH, bH, acc[dt], 0, 0, 0);
                acc[dt] = __builtin_amdgcn_mfma_f32_16x16x32_bf16(aH, bL, acc[dt], 0, 0, 0);
                acc[dt] = __builtin_amdgcn_mfma_f32_16x16x32_bf16(aL, bH, acc[dt], 0, 0, 0);
            }
        }
        if (g < 3) {
#pragma unroll
            for (int i = 0; i < 8; ++i) cur[i] = nxt[i];
#pragma unroll
            for (int i = 0; i < 4; ++i) curl[i] = nxtl[i];
        }
    }

    // ---- accumulate KVT into ws: element (m = 16w+4q+r, d = 16dt+c) ----
    const size_t kvbase = ((size_t)((st * NB + n) * HH + h)) * 4096;
#pragma unroll
    for (int dt = 0; dt < 4; ++dt)
#pragma unroll
        for (int r = 0; r < 4; ++r)
            atomicAdd(&ws[kvbase + (size_t)(16 * w + 4 * q + r) * 64 + 16 * dt + c],
                      acc[dt][r]);

    // ---- Ksum (fp32, exact): reduce per-thread partials; scr overlays VtL ----
    float (*scr)[64] = (float(*)[64])VtL;   // 4 KB of the 9 KB tile
    __syncthreads();                        // last MFMA reads of VtL complete
    scr[sp][4 * d4 + 0] = ksum[0];
    scr[sp][4 * d4 + 1] = ksum[1];
    scr[sp][4 * d4 + 2] = ksum[2];
    scr[sp][4 * d4 + 3] = ksum[3];
    __syncthreads();
    if (t < 64) {
        float s = 0.f;
#pragma unroll
        for (int i = 0; i < 16; ++i) s += scr[i][t];
        atomicAdd(&ws[KVTOT + ((size_t)(st * NB + n) * HH + h) * 64 + t], s);
    }
}

// ---------------- Phase 2 (split-bf16 MFMA): out[l][m] = (phiQ[l]·KVT[m]) * Z[l] -------
// grid: 1024 = st(2)*n(4)*h(16)*lchunk(8, 256 rows each); block 256 (4 waves)
__global__ __launch_bounds__(256) void out_kernel(
    const float* __restrict__ q1, const float* __restrict__ q2,
    const float* __restrict__ ws, float* __restrict__ out)
{
    const int b = blockIdx.x;
    const int lc = b & 7;
    const int h = (b >> 3) & 15;
    const int n = (b >> 7) & 3;
    const int st = (b >> 9) & 1;
    const float* Q = st ? q2 : q1;
    float* O = out + (size_t)st * ((size_t)NB * LL * HH * DD);

    __shared__ __align__(16) unsigned short BtH[64][72];  // KVT[m][d] hi
    __shared__ __align__(16) unsigned short BtL[64][72];  // KVT[m][d] lo
    __shared__ float Ks[64];
    __shared__ float Zl[256];

    const int t = threadIdx.x;
    const int lane = t & 63;
    const int w = t >> 6;          // wave: l-strip [64w, 64w+64)
    const int c = lane & 15;
    const int q = lane >> 4;
    const size_t kvbase = ((size_t)((st * NB + n) * HH + h)) * 4096;

    // ---- stage KVT -> hi/lo bf16 LDS ----
    {
        const int m = t >> 2;
        const int dbase = (t & 3) * 16;
#pragma unroll
        for (int i = 0; i < 4; ++i) {
            const int d0 = dbase + 4 * i;
            const float4 kv = *(const float4*)&ws[kvbase + (size_t)m * 64 + d0];
            unsigned int hp, lp;
            split_pack(kv.x, kv.y, hp, lp);
            *(unsigned int*)&BtH[m][d0]     = hp; *(unsigned int*)&BtL[m][d0]     = lp;
            split_pack(kv.z, kv.w, hp, lp);
            *(unsigned int*)&BtH[m][d0 + 2] = hp; *(unsigned int*)&BtL[m][d0 + 2] = lp;
        }
    }
    if (t < 64) Ks[t] = ws[KVTOT + ((size_t)(st * NB + n) * HH + h) * 64 + t];
    __syncthreads();

    const int lbase = lc * 256;

    // ---- Z[l] in fp32: thread t owns row l = lbase + t ----
    {
        const float* qr = &Q[((size_t)((size_t)n * LL + lbase + t) * HH + h) * EE];
        float z = 0.f;
#pragma unroll
        for (int d = 0; d < 64; d += 4) {
            const float4 qv = *(const float4*)&qr[d];
            z += phi(qv.x) * Ks[d] + phi(qv.y) * Ks[d + 1]
               + phi(qv.z) * Ks[d + 2] + phi(qv.w) * Ks[d + 3];
        }
        Zl[t] = 1.f / (z + 1e-6f);
    }

    // ---- B-fragments resident (hi+lo), reused across all l-tiles ----
    short8 bH[8], bL[8];
#pragma unroll
    for (int mt = 0; mt < 4; ++mt)
#pragma unroll
        for (int ks = 0; ks < 2; ++ks) {
            bH[2 * mt + ks] = *(const short8*)&BtH[16 * mt + c][32 * ks + 8 * q];
            bL[2 * mt + ks] = *(const short8*)&BtL[16 * mt + c][32 * ks + 8 * q];
        }
    __syncthreads();   // Zl visibility for epilogue

    floatx4 acc[16];
#pragma unroll
    for (int i = 0; i < 16; ++i) acc[i] = (floatx4){0.f, 0.f, 0.f, 0.f};

#pragma unroll
    for (int lt = 0; lt < 4; ++lt) {
        const int l = lbase + 64 * w + 16 * lt + c;
        const float* qr = &Q[((size_t)((size_t)n * LL + l) * HH + h) * EE];
#pragma unroll
        for (int ks = 0; ks < 2; ++ks) {
            const int d0 = 32 * ks + 8 * q;
            const float4 qa = *(const float4*)&qr[d0];
            const float4 qb = *(const float4*)&qr[d0 + 4];
            const float p[8] = {phi(qa.x), phi(qa.y), phi(qa.z), phi(qa.w),
                                phi(qb.x), phi(qb.y), phi(qb.z), phi(qb.w)};
            short8 aH, aL;
#pragma unroll
            for (int j = 0; j < 8; ++j) {
                const unsigned int hb = f2bf(p[j]);
                aH[j] = (short)hb;
                aL[j] = (short)f2bf(p[j] - __uint_as_float(hb << 16));
            }
#pragma unroll
            for (int mt = 0; mt < 4; ++mt) {
                acc[4 * lt + mt] = __builtin_amdgcn_mfma_f32_16x16x32_bf16(
                    aH, bH[2 * mt + ks], acc[4 * lt + mt], 0, 0, 0);
                acc[4 * lt + mt] = __builtin_amdgcn_mfma_f32_16x16x32_bf16(
                    aH, bL[2 * mt + ks], acc[4 * lt + mt], 0, 0, 0);
                acc[4 * lt + mt] = __builtin_amdgcn_mfma_f32_16x16x32_bf16(
                    aL, bH[2 * mt + ks], acc[4 * lt + mt], 0, 0, 0);
            }
        }
    }

    // ---- epilogue: out element (l = 64w+16lt+4q+r, m = 16mt+c) ----
#pragma unroll
    for (int lt = 0; lt < 4; ++lt) {
#pragma unroll
        for (int r = 0; r < 4; ++r) {
            const int ll = 64 * w + 16 * lt + 4 * q + r;
            const float z = Zl[ll];
            const size_t ro = ((size_t)((size_t)n * LL + lbase + ll) * HH + h) * DD;
#pragma unroll
            for (int mt = 0; mt < 4; ++mt)
                O[ro + 16 * mt + c] = acc[4 * lt + mt][r] * z;
        }
    }
}

extern "C" void kernel_launch(void* const* d_in, const int* in_sizes, int n_in,
                              void* d_out, int out_size, void* d_ws, size_t ws_size,
                              hipStream_t stream) {
    const float* q1  = (const float*)d_in[0];
    const float* k1  = (const float*)d_in[1];
    const float* v1  = (const float*)d_in[2];
    const float* q2  = (const float*)d_in[3];
    const float* k2  = (const float*)d_in[4];
    const float* v2  = (const float*)d_in[5];
    const float* kl1 = (const float*)d_in[6];
    const float* kl2 = (const float*)d_in[7];
    float* ws = (float*)d_ws;
    float* out = (float*)d_out;

    hipMemsetAsync(d_ws, 0, (size_t)WSFLOATS * sizeof(float), stream);
    kv_kernel<<<dim3(1024), dim3(256), 0, stream>>>(k1, v1, k2, v2, kl1, kl2, ws);
    out_kernel<<<dim3(1024), dim3(256), 0, stream>>>(q1, q2, ws, out);
}